// Round 6
// baseline (161.834 us; speedup 1.0000x reference)
//
#include <hip/hip_runtime.h>
#include <cstdint>
#include <cstddef>

// Problem constants
constexpr int N = 4096;
constexpr int B = 32;
constexpr int BN = B * N;             // 131072
constexpr size_t NN = (size_t)N * N;  // 16777216

// Fused-pass tiling: each block owns a TI x TJ tile of W, read ONCE coalesced.
constexpr int TI = 128;               // i-rows per block
constexpr int TJ = 128;               // j-cols per block
constexpr int NIT = N / TI;           // 32 it partials (partSW copies)
constexpr int NJT = N / TJ;           // 32 jt partials (partSWT copies)
constexpr int ISUB = 64;              // rows per LDS sub-tile
constexpr int LDT = TJ + 8;           // 136 bf16: row stride (16B-aligned rows)

constexpr float ALPHA = 0.025f;
constexpr float BETA = 0.00025f;
constexpr float T_NOW = 10.0f;
constexpr float INV_EXP_TAU = 0.02f;          // 1/50
constexpr float INV_TAU_V = 0.98019867f;      // exp(-1/50)
constexpr float INV_TAU_I = 0.36787944f;      // exp(-1)

typedef __attribute__((ext_vector_type(8))) short short8;
typedef __attribute__((ext_vector_type(4))) float f32x4;

__device__ inline unsigned short f2bf(float f) {
  uint32_t u = __float_as_uint(f);
  u += 0x7FFFu + ((u >> 16) & 1u);   // RNE
  return (unsigned short)(u >> 16);
}

// W-update recomputed on the fly:
//   u = clip(w + BETA - fac_row * exp(|mst_row - mst_col|/50), 0, 1); keep w where w<=0
__device__ inline float wupd(float w, float mrow, float frow, float mcol) {
  float d = fabsf(mrow - mcol);
  float u = w + BETA - frow * __expf(d * INV_EXP_TAU);
  u = fminf(fmaxf(u, 0.0f), 1.0f);
  return (w > 0.0f) ? u : w;
}

// ---------------------------------------------------------------------------
// Pass A: per-neuron spike masks + max_st + rowfac; writes S (f32) and S_bf
// (bf16 copy, the MFMA A-matrix).
// ---------------------------------------------------------------------------
__global__ __launch_bounds__(256) void pass_a(
    const float* __restrict__ mem_pot, const float* __restrict__ mem_pot_p,
    const float* __restrict__ st, float* __restrict__ S_out,
    unsigned short* __restrict__ S_bf,
    uint32_t* __restrict__ maskS, uint32_t* __restrict__ maskSP,
    float* __restrict__ max_st, float* __restrict__ rowfac) {
  int j = blockIdx.x * blockDim.x + threadIdx.x;
  if (j >= N) return;
  float stj = st[j];
  uint32_t ms = 0u, msp = 0u;
  float maxv = -3.0e38f;
  #pragma unroll
  for (int b = 0; b < B; ++b) {
    float p = mem_pot[b * N + j];
    float pp = mem_pot_p[b * N + j];
    bool s = (p - 1.0f) > 0.0f;
    bool sp = ((pp - 1.0f) - ALPHA) > 0.0f;
    S_out[b * N + j] = s ? 1.0f : 0.0f;
    S_bf[b * N + j] = s ? 0x3F80u : 0u;   // bf16 1.0 / 0.0
    ms |= (uint32_t)s << b;
    msp |= (uint32_t)sp << b;
    maxv = fmaxf(maxv, s ? T_NOW : stj);
  }
  maskS[j] = ms;
  maskSP[j] = msp;
  max_st[j] = maxv;
  rowfac[j] = msp ? ALPHA : 0.0f;
}

// ---------------------------------------------------------------------------
// Fused single-W-read pass. Block (jt, it) owns W[i0:i0+128][j0:j0+128]:
//   - loads the tile ONCE, coalesced float4, in 2 sub-tiles of 64x128
//   - computes Wnew (wupd), writes W_out nontemporal (exact 1x coverage)
//   - parks bf16 Wnew in LDS; serves BOTH GEMMs from LDS:
//       gemm0 SW[b,j]  = sum_i S[b,i]*Wnew[i,j]  (waves 0-2, col-frags, u16)
//       gemm1 SWT[b,i] = sum_j S[b,j]*Wnew[i,j]  (wave 3,    row-frags, b128)
//   - S_bf A-fragments preloaded to registers (no global loads in MFMA loops)
//   - partial sums -> partSW[it][b][j] and partSWT[jt][b][i] (no atomics)
// MFMA layouts (verified rounds 0-4): A[m=lane&15][k=quad*8+e],
// B[k=quad*8+e][n=lane&15], C/D: col=lane&15, row=quad*4+reg.
// ---------------------------------------------------------------------------
__global__ __launch_bounds__(256, 3) void pass_fused(
    const float* __restrict__ W, const unsigned short* __restrict__ S_bf,
    const float* __restrict__ max_st, const float* __restrict__ rowfac,
    float* __restrict__ Wout, float* __restrict__ partSW,
    float* __restrict__ partSWT) {
  __shared__ __align__(16) unsigned short tile[ISUB * LDT];  // 17408 B
  __shared__ float mstI[TI];
  __shared__ float facI[TI];
  __shared__ float mstJ[TJ];

  int tid = threadIdx.x;
  int wv = tid >> 6;
  int lane = tid & 63;
  int quad = lane >> 4;
  int nl = lane & 15;
  int jt = blockIdx.x;               // 0..31
  int it = blockIdx.y;               // 0..31
  int i0 = it * TI;
  int j0 = jt * TJ;

  uint32_t* tileU32 = (uint32_t*)tile;

  // thread mapping for the stage phase: 8 row-stripes x 32 float4-cols
  int row8 = tid >> 5;               // 0..7
  int c4 = tid & 31;                 // float4 column

  // issue sub-tile 0 loads (64 rows x 128 cols; 8 float4 per thread)
  float4 pf[8];
  {
    const float* base = W + (size_t)(i0 + row8) * N + j0 + c4 * 4;
    #pragma unroll
    for (int p = 0; p < 8; ++p)
      pf[p] = *(const float4*)(base + (size_t)(p * 8) * N);
  }

  // stage per-row/col update vectors
  if (tid < TI) {
    mstI[tid] = max_st[i0 + tid];
    facI[tid] = rowfac[i0 + tid];
  } else {
    mstJ[tid - TI] = max_st[j0 + (tid - TI)];
  }

  // A-fragment preload (wave-specialized; paths have disjoint lifetimes)
  short8 aG0[4], aG1[4], aJ0[4], aJ1[4];
  if (wv < 3) {
    #pragma unroll
    for (int c = 0; c < 4; ++c) {
      aG0[c] = *(const short8*)(S_bf + (size_t)nl * N + i0 + c * 32 + quad * 8);
      aG1[c] = *(const short8*)(S_bf + (size_t)(nl + 16) * N + i0 + c * 32 + quad * 8);
    }
  } else {
    #pragma unroll
    for (int c = 0; c < 4; ++c) {
      aJ0[c] = *(const short8*)(S_bf + (size_t)nl * N + j0 + c * 32 + quad * 8);
      aJ1[c] = *(const short8*)(S_bf + (size_t)(nl + 16) * N + j0 + c * 32 + quad * 8);
    }
  }
  __syncthreads();   // mstI/facI/mstJ ready

  // gemm0 accumulators (waves 0-2): up to 3 n-tiles x 2 batch-halves
  f32x4 accG0[3], accG1[3];
  #pragma unroll
  for (int t = 0; t < 3; ++t) {
    accG0[t] = (f32x4){0.f, 0.f, 0.f, 0.f};
    accG1[t] = (f32x4){0.f, 0.f, 0.f, 0.f};
  }

  #pragma unroll
  for (int isub = 0; isub < TI / ISUB; ++isub) {
    // ---- stage: wupd + W_out store + bf16 -> LDS ----
    float4 mj = *(const float4*)(mstJ + c4 * 4);
    #pragma unroll
    for (int p = 0; p < 8; ++p) {
      int r = p * 8 + row8;                       // row within sub-tile
      int ig = i0 + isub * ISUB + r;
      float mi = mstI[isub * ISUB + r];
      float fi = facI[isub * ISUB + r];
      f32x4 u;
      u[0] = wupd(pf[p].x, mi, fi, mj.x);
      u[1] = wupd(pf[p].y, mi, fi, mj.y);
      u[2] = wupd(pf[p].z, mi, fi, mj.z);
      u[3] = wupd(pf[p].w, mi, fi, mj.w);
      __builtin_nontemporal_store(u, (f32x4*)(Wout + (size_t)ig * N + j0 + c4 * 4));
      uint32_t d0 = (uint32_t)f2bf(u[0]) | ((uint32_t)f2bf(u[1]) << 16);
      uint32_t d1 = (uint32_t)f2bf(u[2]) | ((uint32_t)f2bf(u[3]) << 16);
      uint2 dd; dd.x = d0; dd.y = d1;
      *(uint2*)&tileU32[r * (LDT / 2) + c4 * 2] = dd;
    }
    // issue next sub-tile's loads (overlap with MFMA phase)
    if (isub + 1 < TI / ISUB) {
      const float* base =
          W + (size_t)(i0 + (isub + 1) * ISUB + row8) * N + j0 + c4 * 4;
      #pragma unroll
      for (int p = 0; p < 8; ++p)
        pf[p] = *(const float4*)(base + (size_t)(p * 8) * N);
    }
    __syncthreads();   // tile writes visible

    // ---- MFMA phase (pure LDS + MFMA) ----
    if (wv < 3) {
      // gemm0: n-tiles js = wv, wv+3, wv+6; K = this sub-tile's 64 rows
      #pragma unroll
      for (int t = 0; t < 3; ++t) {
        int js = wv + 3 * t;
        if (js < 8) {
          #pragma unroll
          for (int kstep = 0; kstep < 2; ++kstep) {
            int kl = kstep * 32 + quad * 8;
            int c = isub * 2 + kstep;             // compile-time (all unrolled)
            short8 b;
            #pragma unroll
            for (int e = 0; e < 8; ++e)
              b[e] = (short)tile[(kl + e) * LDT + js * 16 + nl];
            accG0[t] = __builtin_amdgcn_mfma_f32_16x16x32_bf16(aG0[c], b, accG0[t], 0, 0, 0);
            accG1[t] = __builtin_amdgcn_mfma_f32_16x16x32_bf16(aG1[c], b, accG1[t], 0, 0, 0);
          }
        }
      }
    } else {
      // gemm1: 4 i-groups of 16; K = full TJ=128; complete per isub
      #pragma unroll
      for (int g = 0; g < 4; ++g) {
        int il = g * 16 + nl;                     // row within sub-tile
        f32x4 g0 = {0.f, 0.f, 0.f, 0.f}, g1 = {0.f, 0.f, 0.f, 0.f};
        #pragma unroll
        for (int kstep = 0; kstep < 4; ++kstep) {
          int kl = kstep * 32 + quad * 8;
          short8 bfr = *(const short8*)&tile[il * LDT + kl];
          g0 = __builtin_amdgcn_mfma_f32_16x16x32_bf16(aJ0[kstep], bfr, g0, 0, 0, 0);
          g1 = __builtin_amdgcn_mfma_f32_16x16x32_bf16(aJ1[kstep], bfr, g1, 0, 0, 0);
        }
        int iglob = i0 + isub * ISUB + il;
        size_t basew = (size_t)jt * BN + iglob;
        #pragma unroll
        for (int r = 0; r < 4; ++r) {
          partSWT[basew + (size_t)(quad * 4 + r) * N] = g0[r];
          partSWT[basew + (size_t)(16 + quad * 4 + r) * N] = g1[r];
        }
      }
    }
    if (isub + 1 < TI / ISUB) __syncthreads();  // tile reads done before overwrite
  }

  // epilogue: gemm0 partial stores (K=128 fully accumulated)
  if (wv < 3) {
    size_t baseit = (size_t)it * BN;
    #pragma unroll
    for (int t = 0; t < 3; ++t) {
      int js = wv + 3 * t;
      if (js < 8) {
        int jg = j0 + js * 16 + nl;
        #pragma unroll
        for (int r = 0; r < 4; ++r) {
          partSW[baseit + (size_t)(quad * 4 + r) * N + jg] = accG0[t][r];
          partSW[baseit + (size_t)(16 + quad * 4 + r) * N + jg] = accG1[t][r];
        }
      }
    }
  }
}

// ---------------------------------------------------------------------------
// Pass D: reduce partials, integrate + leak + reset + refractory.
// ---------------------------------------------------------------------------
__global__ __launch_bounds__(256) void pass_d(
    const float* __restrict__ inp, const float* __restrict__ mem_pot,
    const float* __restrict__ mem_cur, const float* __restrict__ mem_pot_p,
    const float* __restrict__ mem_cur_p, const int* __restrict__ refrac_in,
    const uint32_t* __restrict__ maskS, const uint32_t* __restrict__ maskSP,
    const float* __restrict__ partSW, const float* __restrict__ partSWT,
    float* __restrict__ pot_out, float* __restrict__ cur_out,
    float* __restrict__ potp_out, float* __restrict__ curp_out,
    float* __restrict__ refrac_out) {
  int e = blockIdx.x * 256 + threadIdx.x;
  int b = e >> 12;
  int j = e & (N - 1);

  float SW = 0.0f, SWT = 0.0f;
  #pragma unroll
  for (int c = 0; c < NIT; ++c) SW += partSW[(size_t)c * BN + e];
  #pragma unroll
  for (int c = 0; c < NJT; ++c) SWT += partSWT[(size_t)c * BN + e];

  int r = refrac_in[e];
  int rd = (r > 0) ? (r - 1) : r;
  bool active = (rd == 0);
  bool s = (maskS[j] >> b) & 1u;
  bool sp = (maskSP[j] >> b) & 1u;
  float cur = mem_cur[e], pot = mem_pot[e];
  float curp = mem_cur_p[e], potp = mem_pot_p[e];

  float cur_n = active ? (inp[e] + SW + cur) : cur;
  float curp_n = active ? (SWT + curp) : curp;
  float pot_n = active ? (cur_n + pot) : pot;
  float potp_n = active ? (curp_n + potp) : potp;

  pot_n *= INV_TAU_V;
  cur_n *= INV_TAU_I;
  potp_n *= INV_TAU_V;
  curp_n *= INV_TAU_I;

  if (s) pot_n = 0.0f;
  if (sp) potp_n = 0.0f;
  int rn = s ? 2 : rd;

  pot_out[e] = pot_n;
  cur_out[e] = cur_n;
  potp_out[e] = potp_n;
  curp_out[e] = curp_n;
  refrac_out[e] = (float)rn;
}

// ---------------------------------------------------------------------------
extern "C" void kernel_launch(void* const* d_in, const int* in_sizes, int n_in,
                              void* d_out, int out_size, void* d_ws, size_t ws_size,
                              hipStream_t stream) {
  const float* inp = (const float*)d_in[0];
  const float* W = (const float*)d_in[1];
  const float* mem_pot = (const float*)d_in[2];
  const float* mem_cur = (const float*)d_in[3];
  const float* mem_pot_p = (const float*)d_in[4];
  const float* mem_cur_p = (const float*)d_in[5];
  const float* st = (const float*)d_in[6];
  const int* refrac = (const int*)d_in[7];

  float* out = (float*)d_out;
  float* S_out = out;
  float* pot_out = out + BN;
  float* W_out = out + 2 * (size_t)BN;
  float* cur_out = W_out + NN;
  float* potp_out = cur_out + BN;
  float* curp_out = potp_out + BN;
  float* refrac_out = curp_out + BN;

  // Workspace layout (16B-aligned), ~32.6 MB total
  uint32_t* maskS = (uint32_t*)d_ws;                      // 16 KB
  uint32_t* maskSP = maskS + N;                           // 16 KB
  float* max_st = (float*)(maskSP + N);                   // 16 KB
  float* rowfac = max_st + N;                             // 16 KB
  unsigned short* S_bf = (unsigned short*)(rowfac + N);   // 256 KB
  float* partSW = (float*)(S_bf + BN);                    // NIT*BN*4 = 16 MB
  float* partSWT = partSW + (size_t)NIT * BN;             // NJT*BN*4 = 16 MB

  pass_a<<<N / 256, 256, 0, stream>>>(mem_pot, mem_pot_p, st, S_out, S_bf,
                                      maskS, maskSP, max_st, rowfac);
  pass_fused<<<dim3(NJT, NIT), 256, 0, stream>>>(W, S_bf, max_st, rowfac,
                                                 W_out, partSW, partSWT);
  pass_d<<<BN / 256, 256, 0, stream>>>(inp, mem_pot, mem_cur, mem_pot_p,
                                       mem_cur_p, refrac, maskS, maskSP,
                                       partSW, partSWT, pot_out, cur_out,
                                       potp_out, curp_out, refrac_out);
}

// Round 7
// 154.984 us; speedup vs baseline: 1.0442x; 1.0442x over previous
//
#include <hip/hip_runtime.h>
#include <cstdint>
#include <cstddef>

// Problem constants
constexpr int N = 4096;
constexpr int B = 32;
constexpr int BN = B * N;             // 131072
constexpr size_t NN = (size_t)N * N;  // 16777216

// Two-family GEMM pass:
//  Family A (gemm1 + W_out): 256 blocks = (it 0..31) x (jc 0..7)
//     i-panel 128 rows, j-chunk 512 (4 subtiles of 128). K accum = 512.
//  Family B (gemm0):         512 blocks = (jt 0..31) x (ic 0..15)
//     j-panel 128 cols, i-chunk 256 (4 subtiles of 64).  K accum = 256.
constexpr int ABLK = 256;
constexpr int BBLK = 512;
constexpr int NPSWT = 8;              // partSWT copies (jc)
constexpr int NPSW = 16;              // partSW copies (ic)
constexpr int LDTB = 136;             // family B tile row stride (bf16 elems)

constexpr float ALPHA = 0.025f;
constexpr float BETA = 0.00025f;
constexpr float T_NOW = 10.0f;
constexpr float INV_EXP_TAU = 0.02f;          // 1/50
constexpr float INV_TAU_V = 0.98019867f;      // exp(-1/50)
constexpr float INV_TAU_I = 0.36787944f;      // exp(-1)

typedef __attribute__((ext_vector_type(8))) short short8;
typedef __attribute__((ext_vector_type(4))) float f32x4;

__device__ inline unsigned short f2bf(float f) {
  uint32_t u = __float_as_uint(f);
  u += 0x7FFFu + ((u >> 16) & 1u);   // RNE
  return (unsigned short)(u >> 16);
}

// W-update recomputed on the fly:
//   u = clip(w + BETA - fac_row * exp(|mst_row - mst_col|/50), 0, 1); keep w where w<=0
__device__ inline float wupd(float w, float mrow, float frow, float mcol) {
  float d = fabsf(mrow - mcol);
  float u = w + BETA - frow * __expf(d * INV_EXP_TAU);
  u = fminf(fmaxf(u, 0.0f), 1.0f);
  return (w > 0.0f) ? u : w;
}

// ---------------------------------------------------------------------------
// Pass A: per-neuron spike masks + max_st + rowfac; writes S (f32) and S_bf.
// ---------------------------------------------------------------------------
__global__ __launch_bounds__(256) void pass_a(
    const float* __restrict__ mem_pot, const float* __restrict__ mem_pot_p,
    const float* __restrict__ st, float* __restrict__ S_out,
    unsigned short* __restrict__ S_bf,
    uint32_t* __restrict__ maskS, uint32_t* __restrict__ maskSP,
    float* __restrict__ max_st, float* __restrict__ rowfac) {
  int j = blockIdx.x * blockDim.x + threadIdx.x;
  if (j >= N) return;
  float stj = st[j];
  uint32_t ms = 0u, msp = 0u;
  float maxv = -3.0e38f;
  #pragma unroll
  for (int b = 0; b < B; ++b) {
    float p = mem_pot[b * N + j];
    float pp = mem_pot_p[b * N + j];
    bool s = (p - 1.0f) > 0.0f;
    bool sp = ((pp - 1.0f) - ALPHA) > 0.0f;
    S_out[b * N + j] = s ? 1.0f : 0.0f;
    S_bf[b * N + j] = s ? 0x3F80u : 0u;   // bf16 1.0 / 0.0
    ms |= (uint32_t)s << b;
    msp |= (uint32_t)sp << b;
    maxv = fmaxf(maxv, s ? T_NOW : stj);
  }
  maskS[j] = ms;
  maskSP[j] = msp;
  max_st[j] = maxv;
  rowfac[j] = msp ? ALPHA : 0.0f;
}

// ---------------------------------------------------------------------------
// Two-family GEMM pass (one launch; block-uniform branch).
// MFMA layouts (verified rounds 0-6): A[m=lane&15][k=quad*8+e],
// B[k=quad*8+e][n=lane&15], C/D: col=lane&15, row=quad*4+reg.
// Family A LDS tile uses 16B-unit XOR swizzle: unit' = unit ^ (row&7)
// (row stride 256B => without swizzle all 16 n-lanes hit the same banks).
// ---------------------------------------------------------------------------
__global__ __launch_bounds__(256, 3) void pass_gemms(
    const float* __restrict__ W, const unsigned short* __restrict__ S_bf,
    const float* __restrict__ max_st, const float* __restrict__ rowfac,
    float* __restrict__ Wout, float* __restrict__ partSW,
    float* __restrict__ partSWT) {
  __shared__ __align__(16) char smem[33792];

  int tid = threadIdx.x;
  int wv = tid >> 6;
  int lane = tid & 63;
  int quad = lane >> 4;
  int nl = lane & 15;
  int row8 = tid >> 5;               // 0..7 (stage-phase row stripe)
  int c4 = tid & 31;                 // float4 column 0..31

  if (blockIdx.x < ABLK) {
    // =================== Family A: gemm1 (SWT) + W_out ===================
    int it = blockIdx.x & 31;
    int jc = blockIdx.x >> 5;        // 0..7
    int i0 = it * 128;
    float* mstIA = (float*)(smem + 32768);
    float* facIA = mstIA + 128;

    if (tid < 128) {
      mstIA[tid] = max_st[i0 + tid];
      facIA[tid] = rowfac[i0 + tid];
    }

    f32x4 acc[2][2];                 // [ntile][batch-half]
    #pragma unroll
    for (int a = 0; a < 2; ++a)
      #pragma unroll
      for (int h = 0; h < 2; ++h) acc[a][h] = (f32x4){0.f, 0.f, 0.f, 0.f};

    __syncthreads();                 // mstIA/facIA ready

    #pragma unroll 1
    for (int jsub = 0; jsub < 4; ++jsub) {
      int jb = jc * 512 + jsub * 128;
      // load 128x128 W sub-panel: 16 float4 per thread, rows p*8+row8
      float4 pf[16];
      const float* wb = W + (size_t)(i0 + row8) * N + jb + c4 * 4;
      #pragma unroll
      for (int p = 0; p < 16; ++p)
        pf[p] = *(const float4*)(wb + (size_t)(p * 8) * N);
      // A-fragments for this j-window (issued early; complete during stage)
      short8 aA0[4], aA1[4];
      #pragma unroll
      for (int ks = 0; ks < 4; ++ks) {
        int kg = jb + ks * 32 + quad * 8;
        aA0[ks] = *(const short8*)(S_bf + (size_t)nl * N + kg);
        aA1[ks] = *(const short8*)(S_bf + (size_t)(nl + 16) * N + kg);
      }
      float4 mj4 = *(const float4*)(max_st + jb + c4 * 4);

      #pragma unroll
      for (int p = 0; p < 16; ++p) {
        int r = p * 8 + row8;
        float mi = mstIA[r];
        float fi = facIA[r];
        f32x4 u;
        u[0] = wupd(pf[p].x, mi, fi, mj4.x);
        u[1] = wupd(pf[p].y, mi, fi, mj4.y);
        u[2] = wupd(pf[p].z, mi, fi, mj4.z);
        u[3] = wupd(pf[p].w, mi, fi, mj4.w);
        __builtin_nontemporal_store(
            u, (f32x4*)(Wout + (size_t)(i0 + r) * N + jb + c4 * 4));
        uint32_t d0 = (uint32_t)f2bf(u[0]) | ((uint32_t)f2bf(u[1]) << 16);
        uint32_t d1 = (uint32_t)f2bf(u[2]) | ((uint32_t)f2bf(u[3]) << 16);
        uint2 dd; dd.x = d0; dd.y = d1;
        // swizzled write: unit (c4>>1) ^ (r&7); 8B-half select by c4&1
        *(uint2*)(smem + r * 256 + ((((c4 >> 1) ^ (r & 7))) << 4) +
                  ((c4 & 1) << 3)) = dd;
      }
      __syncthreads();               // tile ready

      // gemm1 MFMA: wave owns rows wv*32..wv*32+31 (2 n-tiles of 16 i's)
      #pragma unroll
      for (int ks = 0; ks < 4; ++ks) {
        #pragma unroll
        for (int nt = 0; nt < 2; ++nt) {
          int rr = wv * 32 + nt * 16 + nl;       // tile row (= i local)
          short8 bfr = *(const short8*)(
              smem + rr * 256 + ((((ks * 4 + quad) ^ (rr & 7))) << 4));
          acc[nt][0] =
              __builtin_amdgcn_mfma_f32_16x16x32_bf16(aA0[ks], bfr, acc[nt][0], 0, 0, 0);
          acc[nt][1] =
              __builtin_amdgcn_mfma_f32_16x16x32_bf16(aA1[ks], bfr, acc[nt][1], 0, 0, 0);
        }
      }
      if (jsub < 3) __syncthreads(); // reads done before overwrite
    }

    // epilogue: one partSWT store (K=512 accumulated)
    size_t baseA = (size_t)jc * BN;
    #pragma unroll
    for (int nt = 0; nt < 2; ++nt) {
      int ig = i0 + wv * 32 + nt * 16 + nl;
      #pragma unroll
      for (int r = 0; r < 4; ++r) {
        partSWT[baseA + (size_t)(quad * 4 + r) * N + ig] = acc[nt][0][r];
        partSWT[baseA + (size_t)(16 + quad * 4 + r) * N + ig] = acc[nt][1][r];
      }
    }
  } else {
    // =================== Family B: gemm0 (SW) ===================
    int idx = blockIdx.x - ABLK;
    int jt = idx & 31;
    int ic = idx >> 5;               // 0..15
    int j0 = jt * 128;
    int ibase = ic * 256;
    unsigned short* tileB = (unsigned short*)smem;      // [64][LDTB]
    float* mstIB = (float*)(smem + 17408);
    float* facIB = mstIB + 256;
    float* mstJB = facIB + 256;

    mstIB[tid] = max_st[ibase + tid];
    facIB[tid] = rowfac[ibase + tid];
    if (tid < 128) mstJB[tid] = max_st[j0 + tid];

    float4 pf[8];
    {
      const float* wb = W + (size_t)(ibase + row8) * N + j0 + c4 * 4;
      #pragma unroll
      for (int p = 0; p < 8; ++p)
        pf[p] = *(const float4*)(wb + (size_t)(p * 8) * N);
    }

    f32x4 accB[2][2];                // [j-ntile][batch-half]
    #pragma unroll
    for (int a = 0; a < 2; ++a)
      #pragma unroll
      for (int h = 0; h < 2; ++h) accB[a][h] = (f32x4){0.f, 0.f, 0.f, 0.f};

    __syncthreads();                 // mst/fac ready

    #pragma unroll 1
    for (int isub = 0; isub < 4; ++isub) {
      // A-fragments for this i-window (complete during stage)
      short8 aB0[2], aB1[2];
      #pragma unroll
      for (int ks = 0; ks < 2; ++ks) {
        int kg = ibase + isub * 64 + ks * 32 + quad * 8;
        aB0[ks] = *(const short8*)(S_bf + (size_t)nl * N + kg);
        aB1[ks] = *(const short8*)(S_bf + (size_t)(nl + 16) * N + kg);
      }
      float4 mjB = *(const float4*)(mstJB + c4 * 4);
      #pragma unroll
      for (int p = 0; p < 8; ++p) {
        int r = p * 8 + row8;
        float mi = mstIB[isub * 64 + r];
        float fi = facIB[isub * 64 + r];
        float ux = wupd(pf[p].x, mi, fi, mjB.x);
        float uy = wupd(pf[p].y, mi, fi, mjB.y);
        float uz = wupd(pf[p].z, mi, fi, mjB.z);
        float uw = wupd(pf[p].w, mi, fi, mjB.w);
        uint32_t d0 = (uint32_t)f2bf(ux) | ((uint32_t)f2bf(uy) << 16);
        uint32_t d1 = (uint32_t)f2bf(uz) | ((uint32_t)f2bf(uw) << 16);
        uint2 dd; dd.x = d0; dd.y = d1;
        *(uint2*)((char*)tileB + r * (LDTB * 2) + c4 * 8) = dd;
      }
      // prefetch next sub-tile (overlaps MFMA phase)
      if (isub + 1 < 4) {
        const float* wb =
            W + (size_t)(ibase + (isub + 1) * 64 + row8) * N + j0 + c4 * 4;
        #pragma unroll
        for (int p = 0; p < 8; ++p)
          pf[p] = *(const float4*)(wb + (size_t)(p * 8) * N);
      }
      __syncthreads();               // tile ready

      // gemm0 MFMA: wave owns j-ntiles wv*2, wv*2+1 (balanced)
      #pragma unroll
      for (int ks = 0; ks < 2; ++ks) {
        #pragma unroll
        for (int t = 0; t < 2; ++t) {
          int js = wv * 2 + t;
          short8 b;
          #pragma unroll
          for (int e = 0; e < 8; ++e)
            b[e] = (short)tileB[(ks * 32 + quad * 8 + e) * LDTB + js * 16 + nl];
          accB[t][0] =
              __builtin_amdgcn_mfma_f32_16x16x32_bf16(aB0[ks], b, accB[t][0], 0, 0, 0);
          accB[t][1] =
              __builtin_amdgcn_mfma_f32_16x16x32_bf16(aB1[ks], b, accB[t][1], 0, 0, 0);
        }
      }
      if (isub + 1 < 4) __syncthreads();
    }

    // epilogue: one partSW store (K=256 accumulated)
    size_t baseB = (size_t)ic * BN;
    #pragma unroll
    for (int t = 0; t < 2; ++t) {
      int jg = j0 + (wv * 2 + t) * 16 + nl;
      #pragma unroll
      for (int r = 0; r < 4; ++r) {
        partSW[baseB + (size_t)(quad * 4 + r) * N + jg] = accB[t][0][r];
        partSW[baseB + (size_t)(16 + quad * 4 + r) * N + jg] = accB[t][1][r];
      }
    }
  }
}

// ---------------------------------------------------------------------------
// Pass D: reduce partials, integrate + leak + reset + refractory.
// ---------------------------------------------------------------------------
__global__ __launch_bounds__(256) void pass_d(
    const float* __restrict__ inp, const float* __restrict__ mem_pot,
    const float* __restrict__ mem_cur, const float* __restrict__ mem_pot_p,
    const float* __restrict__ mem_cur_p, const int* __restrict__ refrac_in,
    const uint32_t* __restrict__ maskS, const uint32_t* __restrict__ maskSP,
    const float* __restrict__ partSW, const float* __restrict__ partSWT,
    float* __restrict__ pot_out, float* __restrict__ cur_out,
    float* __restrict__ potp_out, float* __restrict__ curp_out,
    float* __restrict__ refrac_out) {
  int e = blockIdx.x * 256 + threadIdx.x;
  int b = e >> 12;
  int j = e & (N - 1);

  float SW = 0.0f, SWT = 0.0f;
  #pragma unroll
  for (int c = 0; c < NPSW; ++c) SW += partSW[(size_t)c * BN + e];
  #pragma unroll
  for (int c = 0; c < NPSWT; ++c) SWT += partSWT[(size_t)c * BN + e];

  int r = refrac_in[e];
  int rd = (r > 0) ? (r - 1) : r;
  bool active = (rd == 0);
  bool s = (maskS[j] >> b) & 1u;
  bool sp = (maskSP[j] >> b) & 1u;
  float cur = mem_cur[e], pot = mem_pot[e];
  float curp = mem_cur_p[e], potp = mem_pot_p[e];

  float cur_n = active ? (inp[e] + SW + cur) : cur;
  float curp_n = active ? (SWT + curp) : curp;
  float pot_n = active ? (cur_n + pot) : pot;
  float potp_n = active ? (curp_n + potp) : potp;

  pot_n *= INV_TAU_V;
  cur_n *= INV_TAU_I;
  potp_n *= INV_TAU_V;
  curp_n *= INV_TAU_I;

  if (s) pot_n = 0.0f;
  if (sp) potp_n = 0.0f;
  int rn = s ? 2 : rd;

  pot_out[e] = pot_n;
  cur_out[e] = cur_n;
  potp_out[e] = potp_n;
  curp_out[e] = curp_n;
  refrac_out[e] = (float)rn;
}

// ---------------------------------------------------------------------------
extern "C" void kernel_launch(void* const* d_in, const int* in_sizes, int n_in,
                              void* d_out, int out_size, void* d_ws, size_t ws_size,
                              hipStream_t stream) {
  const float* inp = (const float*)d_in[0];
  const float* W = (const float*)d_in[1];
  const float* mem_pot = (const float*)d_in[2];
  const float* mem_cur = (const float*)d_in[3];
  const float* mem_pot_p = (const float*)d_in[4];
  const float* mem_cur_p = (const float*)d_in[5];
  const float* st = (const float*)d_in[6];
  const int* refrac = (const int*)d_in[7];

  float* out = (float*)d_out;
  float* S_out = out;
  float* pot_out = out + BN;
  float* W_out = out + 2 * (size_t)BN;
  float* cur_out = W_out + NN;
  float* potp_out = cur_out + BN;
  float* curp_out = potp_out + BN;
  float* refrac_out = curp_out + BN;

  // Workspace layout (16B-aligned), ~12.6 MB total
  uint32_t* maskS = (uint32_t*)d_ws;                      // 16 KB
  uint32_t* maskSP = maskS + N;                           // 16 KB
  float* max_st = (float*)(maskSP + N);                   // 16 KB
  float* rowfac = max_st + N;                             // 16 KB
  unsigned short* S_bf = (unsigned short*)(rowfac + N);   // 256 KB
  float* partSW = (float*)(S_bf + BN);                    // NPSW*BN*4  = 8 MB
  float* partSWT = partSW + (size_t)NPSW * BN;            // NPSWT*BN*4 = 4 MB

  pass_a<<<N / 256, 256, 0, stream>>>(mem_pot, mem_pot_p, st, S_out, S_bf,
                                      maskS, maskSP, max_st, rowfac);
  pass_gemms<<<ABLK + BBLK, 256, 0, stream>>>(W, S_bf, max_st, rowfac,
                                              W_out, partSW, partSWT);
  pass_d<<<BN / 256, 256, 0, stream>>>(inp, mem_pot, mem_cur, mem_pot_p,
                                       mem_cur_p, refrac, maskS, maskSP,
                                       partSW, partSWT, pot_out, cur_out,
                                       potp_out, curp_out, refrac_out);
}